// Round 1
// baseline (253.697 us; speedup 1.0000x reference)
//
#include <hip/hip_runtime.h>
#include <math.h>

#define NBINS 64
#define BATCH_N 884736    // 96*96*96
#define NTOT   1769472    // 2*BATCH_N
#define GBLK 432          // hist blocks per batch: 884736/432 = 2048 voxels/block
#define KBLK 512          // k_minmax blocks
#define HROW 68           // padded joint-hist row stride (bins -1..66)
#define HSZ  4624         // 68*68 floats = 18496 B LDS

// ws layout (bytes):
//   ghist  at   256 : float[2][4096]          (zeroed by k_hist prologue)
//   kblk   at 36864 : uint4[512]               (plain-stored by k_minmax)
//   part   at 65536 : float[2][432][4096]      (fully stored by k_hist)
#define OFF_GHIST 256
#define OFF_KBLK 36864
#define OFF_PART 65536

// monotone float->uint key: max over keys == max over floats
__device__ __forceinline__ unsigned fkey(float x){
    unsigned u = __float_as_uint(x);
    return (u & 0x80000000u) ? ~u : (u | 0x80000000u);
}
__device__ __forceinline__ float fdecode(unsigned k){
    return __uint_as_float((k & 0x80000000u) ? (k ^ 0x80000000u) : ~k);
}

// cubic B-spline weights for bins it0-1..it0+2, u = frac(v) in [0,1)
__device__ __forceinline__ void bw4(float u, float w[4]){
    float um = 1.f - u;
    float u2 = u*u, um2 = um*um;
    w[0] = um2*um*(1.f/6.f);
    w[3] = u2*u*(1.f/6.f);
    w[1] = 0.6666666666666667f - u2 + 0.5f*u2*u;
    w[2] = 0.6666666666666667f - um2 + 0.5f*um2*um;
}

// per-block min/max -> plain store into kblk[block] (no atomics, no memset needed)
__global__ void __launch_bounds__(256)
k_minmax(const float4* __restrict__ t4, const float4* __restrict__ s4,
         int n4, uint4* __restrict__ kblk){
    __shared__ unsigned red[4][4];   // [wave][key]

    unsigned mt=0u, mnt=0u, ms=0u, mns=0u;
    int stride = gridDim.x * blockDim.x;
    for (int i = blockIdx.x*blockDim.x + threadIdx.x; i < n4; i += stride){
        float4 a = t4[i];
        float4 b = s4[i];
        mt  = max(mt,  max(max(fkey(a.x),  fkey(a.y)),  max(fkey(a.z),  fkey(a.w))));
        mnt = max(mnt, max(max(fkey(-a.x), fkey(-a.y)), max(fkey(-a.z), fkey(-a.w))));
        ms  = max(ms,  max(max(fkey(b.x),  fkey(b.y)),  max(fkey(b.z),  fkey(b.w))));
        mns = max(mns, max(max(fkey(-b.x), fkey(-b.y)), max(fkey(-b.z), fkey(-b.w))));
    }
    #pragma unroll
    for (int off = 32; off; off >>= 1){
        mt  = max(mt,  __shfl_down(mt,  off));
        mnt = max(mnt, __shfl_down(mnt, off));
        ms  = max(ms,  __shfl_down(ms,  off));
        mns = max(mns, __shfl_down(mns, off));
    }
    int wid = threadIdx.x >> 6;
    if ((threadIdx.x & 63) == 0){
        red[wid][0] = mt; red[wid][1] = mnt; red[wid][2] = ms; red[wid][3] = mns;
    }
    __syncthreads();
    if (threadIdx.x == 0){
        uint4 q;
        q.x = max(max(red[0][0], red[1][0]), max(red[2][0], red[3][0]));
        q.y = max(max(red[0][1], red[1][1]), max(red[2][1], red[3][1]));
        q.z = max(max(red[0][2], red[1][2]), max(red[2][2], red[3][2]));
        q.w = max(max(red[0][3], red[1][3]), max(red[2][3], red[3][3]));
        kblk[blockIdx.x] = q;
    }
}

// joint histogram via direct LDS f32 atomics into a padded [68][68] tile.
// Each voxel contributes its 4x4 B-spline weight outer product. Pad rows/cols
// absorb the out-of-range bins (-1, 64, 65, 66) exactly like the reference's
// implicit discard; only rows/cols 1..64 are extracted.
// 2048 voxels/block: each thread loads exactly two float4 from t and s.
__global__ void __launch_bounds__(256)
k_hist(const float* __restrict__ t, const float* __restrict__ s,
       const uint4* __restrict__ kblk, float* __restrict__ ghist,
       float* __restrict__ part){
    __shared__ float h[HSZ];
    __shared__ unsigned kred[4][4];

    int tid = threadIdx.x;
    int lane = tid & 63, warp = tid >> 6;
    int b = blockIdx.y;

    // zero ghist for k_reduce (visible at kernel boundary)
    if (b == 0 && blockIdx.x < 8){
        #pragma unroll
        for (int k = 0; k < 4; ++k)
            ghist[blockIdx.x*1024 + k*256 + tid] = 0.f;
    }

    // issue input loads early (independent of the reductions below)
    const float4* t4 = (const float4*)(t + (size_t)b*BATCH_N) + (size_t)blockIdx.x*512;
    const float4* s4 = (const float4*)(s + (size_t)b*BATCH_N) + (size_t)blockIdx.x*512;
    float4 ta = t4[tid], tb = t4[tid + 256];
    float4 sa = s4[tid], sb = s4[tid + 256];

    // zero LDS hist
    for (int i = tid; i < HSZ; i += 256) h[i] = 0.f;

    // reduce the 512 per-block key quads (redundant per block; ~L2-hit)
    unsigned m0=0u, m1=0u, m2=0u, m3=0u;
    #pragma unroll
    for (int i = 0; i < 2; ++i){
        uint4 q = kblk[tid + i*256];
        m0 = max(m0, q.x); m1 = max(m1, q.y);
        m2 = max(m2, q.z); m3 = max(m3, q.w);
    }
    #pragma unroll
    for (int off = 32; off; off >>= 1){
        m0 = max(m0, __shfl_down(m0, off));
        m1 = max(m1, __shfl_down(m1, off));
        m2 = max(m2, __shfl_down(m2, off));
        m3 = max(m3, __shfl_down(m3, off));
    }
    if (lane == 0){
        kred[warp][0] = m0; kred[warp][1] = m1;
        kred[warp][2] = m2; kred[warp][3] = m3;
    }
    __syncthreads();   // covers both h zero-init and kred

    float tmax =  fdecode(max(max(kred[0][0], kred[1][0]), max(kred[2][0], kred[3][0])));
    float tmin = -fdecode(max(max(kred[0][1], kred[1][1]), max(kred[2][1], kred[3][1])));
    float smax =  fdecode(max(max(kred[0][2], kred[1][2]), max(kred[2][2], kred[3][2])));
    float smin = -fdecode(max(max(kred[0][3], kred[1][3]), max(kred[2][3], kred[3][3])));
    float tsc = 64.f / (tmax - tmin);
    float ssc = 64.f / (smax - smin);

    // per-voxel: 4x4 outer-product scatter. vt in [0,64] -> rows it0..it0+3
    // (bin it0-1..it0+2 shifted +1) in 0..67; same for cols. Unconditional.
    #define VOX(tv, sv) do { \
        float vt = ((tv) - tmin) * tsc; \
        float vs = ((sv) - smin) * ssc; \
        int it0 = (int)vt; \
        int is0 = (int)vs; \
        float wt[4], wsv[4]; \
        bw4(vt - (float)it0, wt); \
        bw4(vs - (float)is0, wsv); \
        int bse = it0*HROW + is0; \
        _Pragma("unroll") \
        for (int k = 0; k < 4; ++k){ \
            _Pragma("unroll") \
            for (int j = 0; j < 4; ++j) \
                atomicAdd(&h[bse + k*HROW + j], wt[k]*wsv[j]); \
        } \
    } while(0)

    VOX(ta.x, sa.x); VOX(ta.y, sa.y); VOX(ta.z, sa.z); VOX(ta.w, sa.w);
    VOX(tb.x, sb.x); VOX(tb.y, sb.y); VOX(tb.z, sb.z); VOX(tb.w, sb.w);
    #undef VOX

    __syncthreads();
    // extract inner 64x64 region; lane-consecutive cols -> conflict-free LDS
    // reads (2 lanes/bank) and coalesced global stores.
    float* gp = part + ((size_t)(b*GBLK + blockIdx.x))*4096;
    for (int i = tid; i < 4096; i += 256)
        gp[i] = h[((i >> 6) + 1)*HROW + (i & 63) + 1];
}

// reduce 432 partials/batch -> ghist. grid (4, 2, 27): each thread sums 16
// partials for 4 consecutive bins (float4), loads deeply in flight, then 4
// atomic adds (221K atomics total — negligible).
__global__ void __launch_bounds__(256)
k_reduce(const float* __restrict__ part, float* __restrict__ ghist){
    int b = blockIdx.y;
    int bin4 = (blockIdx.x*256 + threadIdx.x)*4;   // 0..4092
    int p0 = blockIdx.z*16;                        // 27 groups * 16 partials = 432
    const float* base = part + (size_t)(b*GBLK + p0)*4096 + bin4;
    float4 v[16];
    #pragma unroll
    for (int i = 0; i < 16; ++i)
        v[i] = *(const float4*)(base + (size_t)i*4096);
    float4 s;
    s.x = ((v[0].x+v[1].x)+(v[2].x+v[3].x)) + ((v[4].x+v[5].x)+(v[6].x+v[7].x))
        + ((v[8].x+v[9].x)+(v[10].x+v[11].x)) + ((v[12].x+v[13].x)+(v[14].x+v[15].x));
    s.y = ((v[0].y+v[1].y)+(v[2].y+v[3].y)) + ((v[4].y+v[5].y)+(v[6].y+v[7].y))
        + ((v[8].y+v[9].y)+(v[10].y+v[11].y)) + ((v[12].y+v[13].y)+(v[14].y+v[15].y));
    s.z = ((v[0].z+v[1].z)+(v[2].z+v[3].z)) + ((v[4].z+v[5].z)+(v[6].z+v[7].z))
        + ((v[8].z+v[9].z)+(v[10].z+v[11].z)) + ((v[12].z+v[13].z)+(v[14].z+v[15].z));
    s.w = ((v[0].w+v[1].w)+(v[2].w+v[3].w)) + ((v[4].w+v[5].w)+(v[6].w+v[7].w))
        + ((v[8].w+v[9].w)+(v[10].w+v[11].w)) + ((v[12].w+v[13].w)+(v[14].w+v[15].w));
    float* g = ghist + b*4096 + bin4;
    unsafeAtomicAdd(&g[0], s.x);
    unsafeAtomicAdd(&g[1], s.y);
    unsafeAtomicAdd(&g[2], s.z);
    unsafeAtomicAdd(&g[3], s.w);
}

__device__ __forceinline__ float blockReduceSum(float v, float* red){
    #pragma unroll
    for (int off = 32; off; off >>= 1) v += __shfl_down(v, off);
    int wid = threadIdx.x >> 6, lane = threadIdx.x & 63;
    __syncthreads();              // protect red[] from previous round
    if (lane == 0) red[wid] = v;
    __syncthreads();
    return red[0] + red[1] + red[2] + red[3];
}

__global__ void k_final(const float* __restrict__ hist, float* __restrict__ out){
    __shared__ float sh[2*4096];
    __shared__ float red[4];
    int tid = threadIdx.x;
    for (int i = tid; i < 8192; i += 256) sh[i] = hist[i];
    __syncthreads();

    float loc = 0.f;
    for (int i = tid; i < 8192; i += 256) loc += sh[i];
    float total = blockReduceSum(loc, red);
    float inv = 1.f / total;

    float nmi[2];
    for (int b = 0; b < 2; ++b){
        const float* h = sh + b*4096;
        float lj = 0.f;
        for (int i = tid; i < 4096; i += 256){
            float p = h[i]*inv;
            lj += p*logf(p + 1e-12f);
        }
        float Hj = -blockReduceSum(lj, red);
        float lt = 0.f;
        if (tid < 64){
            float r = 0.f;
            for (int j = 0; j < 64; ++j) r += h[tid*64 + j];
            float p = r*inv;
            lt = p*logf(p + 1e-12f);
        }
        float Ht = -blockReduceSum(lt, red);
        float ls = 0.f;
        if (tid < 64){
            float c = 0.f;
            for (int j = 0; j < 64; ++j) c += h[j*64 + tid];
            float p = c*inv;
            ls = p*logf(p + 1e-12f);
        }
        float Hs = -blockReduceSum(ls, red);
        nmi[b] = (Ht + Hs) / Hj;
    }
    if (tid == 0) out[0] = -0.5f*(nmi[0] + nmi[1]);
}

extern "C" void kernel_launch(void* const* d_in, const int* in_sizes, int n_in,
                              void* d_out, int out_size, void* d_ws, size_t ws_size,
                              hipStream_t stream) {
    const float* t = (const float*)d_in[0];
    const float* s = (const float*)d_in[1];
    float* out = (float*)d_out;
    float* ghist = (float*)((char*)d_ws + OFF_GHIST);
    uint4* kblk  = (uint4*)((char*)d_ws + OFF_KBLK);
    float* part  = (float*)((char*)d_ws + OFF_PART);

    // no memset node: kblk plain-stored by k_minmax; ghist zeroed in k_hist;
    // part fully overwritten by k_hist. Kernel boundaries provide visibility.
    k_minmax<<<KBLK, 256, 0, stream>>>((const float4*)t, (const float4*)s, NTOT/4, kblk);
    k_hist<<<dim3(GBLK, 2), 256, 0, stream>>>(t, s, kblk, ghist, part);
    k_reduce<<<dim3(4, 2, 27), 256, 0, stream>>>(part, ghist);
    k_final<<<1, 256, 0, stream>>>(ghist, out);
}

// Round 2
// 252.123 us; speedup vs baseline: 1.0062x; 1.0062x over previous
//
#include <hip/hip_runtime.h>
#include <math.h>

#define NBINS 64
#define BATCH_N 884736    // 96*96*96
#define NTOT   1769472    // 2*BATCH_N
#define GBLK 432          // hist blocks per batch: 884736/432 = 2048 voxels/block
#define KBLK 512          // k_minmax blocks
#define HROW 68           // padded joint-hist row stride (bins -1..66)
#define HSZ  4624         // 68*68 floats = 18496 B LDS

// ws layout (bytes):
//   ghist  at   256 : float[2][4096]          (zeroed by k_hist prologue)
//   kblk   at 36864 : uint4[512]               (plain-stored by k_minmax)
//   part   at 65536 : float[2][432][4096]      (fully stored by k_hist)
#define OFF_GHIST 256
#define OFF_KBLK 36864
#define OFF_PART 65536

// monotone float->uint key: max over keys == max over floats
__device__ __forceinline__ unsigned fkey(float x){
    unsigned u = __float_as_uint(x);
    return (u & 0x80000000u) ? ~u : (u | 0x80000000u);
}
__device__ __forceinline__ float fdecode(unsigned k){
    return __uint_as_float((k & 0x80000000u) ? (k ^ 0x80000000u) : ~k);
}

// cubic B-spline weights for bins it0-1..it0+2, u = frac(v) in [0,1)
__device__ __forceinline__ void bw4(float u, float w[4]){
    float um = 1.f - u;
    float u2 = u*u, um2 = um*um;
    w[0] = um2*um*(1.f/6.f);
    w[3] = u2*u*(1.f/6.f);
    w[1] = 0.6666666666666667f - u2 + 0.5f*u2*u;
    w[2] = 0.6666666666666667f - um2 + 0.5f*um2*um;
}

// per-block min/max -> plain store into kblk[block] (no atomics, no memset needed)
__global__ void __launch_bounds__(256)
k_minmax(const float4* __restrict__ t4, const float4* __restrict__ s4,
         int n4, uint4* __restrict__ kblk){
    __shared__ unsigned red[4][4];   // [wave][key]

    unsigned mt=0u, mnt=0u, ms=0u, mns=0u;
    int stride = gridDim.x * blockDim.x;
    for (int i = blockIdx.x*blockDim.x + threadIdx.x; i < n4; i += stride){
        float4 a = t4[i];
        float4 b = s4[i];
        mt  = max(mt,  max(max(fkey(a.x),  fkey(a.y)),  max(fkey(a.z),  fkey(a.w))));
        mnt = max(mnt, max(max(fkey(-a.x), fkey(-a.y)), max(fkey(-a.z), fkey(-a.w))));
        ms  = max(ms,  max(max(fkey(b.x),  fkey(b.y)),  max(fkey(b.z),  fkey(b.w))));
        mns = max(mns, max(max(fkey(-b.x), fkey(-b.y)), max(fkey(-b.z), fkey(-b.w))));
    }
    #pragma unroll
    for (int off = 32; off; off >>= 1){
        mt  = max(mt,  __shfl_down(mt,  off));
        mnt = max(mnt, __shfl_down(mnt, off));
        ms  = max(ms,  __shfl_down(ms,  off));
        mns = max(mns, __shfl_down(mns, off));
    }
    int wid = threadIdx.x >> 6;
    if ((threadIdx.x & 63) == 0){
        red[wid][0] = mt; red[wid][1] = mnt; red[wid][2] = ms; red[wid][3] = mns;
    }
    __syncthreads();
    if (threadIdx.x == 0){
        uint4 q;
        q.x = max(max(red[0][0], red[1][0]), max(red[2][0], red[3][0]));
        q.y = max(max(red[0][1], red[1][1]), max(red[2][1], red[3][1]));
        q.z = max(max(red[0][2], red[1][2]), max(red[2][2], red[3][2]));
        q.w = max(max(red[0][3], red[1][3]), max(red[2][3], red[3][3]));
        kblk[blockIdx.x] = q;
    }
}

// joint histogram via direct LDS f32 atomics into a padded [68][68] tile.
// Each voxel contributes its 4x4 B-spline weight outer product. Pad rows/cols
// absorb the out-of-range bins (-1, 64, 65, 66) exactly like the reference's
// implicit discard; only rows/cols 1..64 are extracted.
// CRITICAL: unsafeAtomicAdd -> native ds_add_f32 (no-return). Plain atomicAdd
// on LDS f32 compiles to a CAS retry loop (R1: 175 us, VALUBusy 2%).
__global__ void __launch_bounds__(256)
k_hist(const float* __restrict__ t, const float* __restrict__ s,
       const uint4* __restrict__ kblk, float* __restrict__ ghist,
       float* __restrict__ part){
    __shared__ float h[HSZ];
    __shared__ unsigned kred[4][4];

    int tid = threadIdx.x;
    int lane = tid & 63, warp = tid >> 6;
    int b = blockIdx.y;

    // zero ghist for k_reduce (visible at kernel boundary)
    if (b == 0 && blockIdx.x < 8){
        #pragma unroll
        for (int k = 0; k < 4; ++k)
            ghist[blockIdx.x*1024 + k*256 + tid] = 0.f;
    }

    // issue input loads early (independent of the reductions below)
    const float4* t4 = (const float4*)(t + (size_t)b*BATCH_N) + (size_t)blockIdx.x*512;
    const float4* s4 = (const float4*)(s + (size_t)b*BATCH_N) + (size_t)blockIdx.x*512;
    float4 ta = t4[tid], tb = t4[tid + 256];
    float4 sa = s4[tid], sb = s4[tid + 256];

    // zero LDS hist
    for (int i = tid; i < HSZ; i += 256) h[i] = 0.f;

    // reduce the 512 per-block key quads (redundant per block; ~L2-hit)
    unsigned m0=0u, m1=0u, m2=0u, m3=0u;
    #pragma unroll
    for (int i = 0; i < 2; ++i){
        uint4 q = kblk[tid + i*256];
        m0 = max(m0, q.x); m1 = max(m1, q.y);
        m2 = max(m2, q.z); m3 = max(m3, q.w);
    }
    #pragma unroll
    for (int off = 32; off; off >>= 1){
        m0 = max(m0, __shfl_down(m0, off));
        m1 = max(m1, __shfl_down(m1, off));
        m2 = max(m2, __shfl_down(m2, off));
        m3 = max(m3, __shfl_down(m3, off));
    }
    if (lane == 0){
        kred[warp][0] = m0; kred[warp][1] = m1;
        kred[warp][2] = m2; kred[warp][3] = m3;
    }
    __syncthreads();   // covers both h zero-init and kred

    float tmax =  fdecode(max(max(kred[0][0], kred[1][0]), max(kred[2][0], kred[3][0])));
    float tmin = -fdecode(max(max(kred[0][1], kred[1][1]), max(kred[2][1], kred[3][1])));
    float smax =  fdecode(max(max(kred[0][2], kred[1][2]), max(kred[2][2], kred[3][2])));
    float smin = -fdecode(max(max(kred[0][3], kred[1][3]), max(kred[2][3], kred[3][3])));
    float tsc = 64.f / (tmax - tmin);
    float ssc = 64.f / (smax - smin);

    // per-voxel: 4x4 outer-product scatter. vt in [0,64] -> rows it0..it0+3
    // (bin it0-1..it0+2 shifted +1) in 0..67; same for cols. Unconditional.
    #define VOX(tv, sv) do { \
        float vt = ((tv) - tmin) * tsc; \
        float vs = ((sv) - smin) * ssc; \
        int it0 = (int)vt; \
        int is0 = (int)vs; \
        float wt[4], wsv[4]; \
        bw4(vt - (float)it0, wt); \
        bw4(vs - (float)is0, wsv); \
        int bse = it0*HROW + is0; \
        _Pragma("unroll") \
        for (int k = 0; k < 4; ++k){ \
            _Pragma("unroll") \
            for (int j = 0; j < 4; ++j) \
                unsafeAtomicAdd(&h[bse + k*HROW + j], wt[k]*wsv[j]); \
        } \
    } while(0)

    VOX(ta.x, sa.x); VOX(ta.y, sa.y); VOX(ta.z, sa.z); VOX(ta.w, sa.w);
    VOX(tb.x, sb.x); VOX(tb.y, sb.y); VOX(tb.z, sb.z); VOX(tb.w, sb.w);
    #undef VOX

    __syncthreads();
    // extract inner 64x64 region; lane-consecutive cols -> conflict-free LDS
    // reads (2 lanes/bank) and coalesced global stores.
    float* gp = part + ((size_t)(b*GBLK + blockIdx.x))*4096;
    for (int i = tid; i < 4096; i += 256)
        gp[i] = h[((i >> 6) + 1)*HROW + (i & 63) + 1];
}

// reduce 432 partials/batch -> ghist. grid (4, 2, 27): each thread sums 16
// partials for 4 consecutive bins (float4), loads deeply in flight, then 4
// atomic adds (221K atomics total — negligible).
__global__ void __launch_bounds__(256)
k_reduce(const float* __restrict__ part, float* __restrict__ ghist){
    int b = blockIdx.y;
    int bin4 = (blockIdx.x*256 + threadIdx.x)*4;   // 0..4092
    int p0 = blockIdx.z*16;                        // 27 groups * 16 partials = 432
    const float* base = part + (size_t)(b*GBLK + p0)*4096 + bin4;
    float4 v[16];
    #pragma unroll
    for (int i = 0; i < 16; ++i)
        v[i] = *(const float4*)(base + (size_t)i*4096);
    float4 s;
    s.x = ((v[0].x+v[1].x)+(v[2].x+v[3].x)) + ((v[4].x+v[5].x)+(v[6].x+v[7].x))
        + ((v[8].x+v[9].x)+(v[10].x+v[11].x)) + ((v[12].x+v[13].x)+(v[14].x+v[15].x));
    s.y = ((v[0].y+v[1].y)+(v[2].y+v[3].y)) + ((v[4].y+v[5].y)+(v[6].y+v[7].y))
        + ((v[8].y+v[9].y)+(v[10].y+v[11].y)) + ((v[12].y+v[13].y)+(v[14].y+v[15].y));
    s.z = ((v[0].z+v[1].z)+(v[2].z+v[3].z)) + ((v[4].z+v[5].z)+(v[6].z+v[7].z))
        + ((v[8].z+v[9].z)+(v[10].z+v[11].z)) + ((v[12].z+v[13].z)+(v[14].z+v[15].z));
    s.w = ((v[0].w+v[1].w)+(v[2].w+v[3].w)) + ((v[4].w+v[5].w)+(v[6].w+v[7].w))
        + ((v[8].w+v[9].w)+(v[10].w+v[11].w)) + ((v[12].w+v[13].w)+(v[14].w+v[15].w));
    float* g = ghist + b*4096 + bin4;
    unsafeAtomicAdd(&g[0], s.x);
    unsafeAtomicAdd(&g[1], s.y);
    unsafeAtomicAdd(&g[2], s.z);
    unsafeAtomicAdd(&g[3], s.w);
}

__device__ __forceinline__ float blockReduceSum(float v, float* red){
    #pragma unroll
    for (int off = 32; off; off >>= 1) v += __shfl_down(v, off);
    int wid = threadIdx.x >> 6, lane = threadIdx.x & 63;
    __syncthreads();              // protect red[] from previous round
    if (lane == 0) red[wid] = v;
    __syncthreads();
    return red[0] + red[1] + red[2] + red[3];
}

__global__ void k_final(const float* __restrict__ hist, float* __restrict__ out){
    __shared__ float sh[2*4096];
    __shared__ float red[4];
    int tid = threadIdx.x;
    for (int i = tid; i < 8192; i += 256) sh[i] = hist[i];
    __syncthreads();

    float loc = 0.f;
    for (int i = tid; i < 8192; i += 256) loc += sh[i];
    float total = blockReduceSum(loc, red);
    float inv = 1.f / total;

    float nmi[2];
    for (int b = 0; b < 2; ++b){
        const float* h = sh + b*4096;
        float lj = 0.f;
        for (int i = tid; i < 4096; i += 256){
            float p = h[i]*inv;
            lj += p*logf(p + 1e-12f);
        }
        float Hj = -blockReduceSum(lj, red);
        float lt = 0.f;
        if (tid < 64){
            float r = 0.f;
            for (int j = 0; j < 64; ++j) r += h[tid*64 + j];
            float p = r*inv;
            lt = p*logf(p + 1e-12f);
        }
        float Ht = -blockReduceSum(lt, red);
        float ls = 0.f;
        if (tid < 64){
            float c = 0.f;
            for (int j = 0; j < 64; ++j) c += h[j*64 + tid];
            float p = c*inv;
            ls = p*logf(p + 1e-12f);
        }
        float Hs = -blockReduceSum(ls, red);
        nmi[b] = (Ht + Hs) / Hj;
    }
    if (tid == 0) out[0] = -0.5f*(nmi[0] + nmi[1]);
}

extern "C" void kernel_launch(void* const* d_in, const int* in_sizes, int n_in,
                              void* d_out, int out_size, void* d_ws, size_t ws_size,
                              hipStream_t stream) {
    const float* t = (const float*)d_in[0];
    const float* s = (const float*)d_in[1];
    float* out = (float*)d_out;
    float* ghist = (float*)((char*)d_ws + OFF_GHIST);
    uint4* kblk  = (uint4*)((char*)d_ws + OFF_KBLK);
    float* part  = (float*)((char*)d_ws + OFF_PART);

    // no memset node: kblk plain-stored by k_minmax; ghist zeroed in k_hist;
    // part fully overwritten by k_hist. Kernel boundaries provide visibility.
    k_minmax<<<KBLK, 256, 0, stream>>>((const float4*)t, (const float4*)s, NTOT/4, kblk);
    k_hist<<<dim3(GBLK, 2), 256, 0, stream>>>(t, s, kblk, ghist, part);
    k_reduce<<<dim3(4, 2, 27), 256, 0, stream>>>(part, ghist);
    k_final<<<1, 256, 0, stream>>>(ghist, out);
}

// Round 3
// 97.621 us; speedup vs baseline: 2.5988x; 2.5827x over previous
//
#include <hip/hip_runtime.h>
#include <math.h>

#define NBINS 64
#define BATCH_N 884736    // 96*96*96
#define NTOT   1769472    // 2*BATCH_N
#define ROWB  80          // tile row stride bytes (64 voxels + 16 pad, 16B aligned)
#define TILE_B 5440       // 68*80 bytes per tile (rows -1..66 padded)
#define WAVE_B 10880      // A+B tiles per wave
#define MROW 66           // merge region row stride (floats)
#define QS 190.0f         // weight quantization scale (max w=2/3 -> 127)
#define GBLK 216          // k_gemm blocks per batch (4 waves each)
#define GWAVES 864        // waves per batch: 13824/864 = exactly 16 chunks/wave
#define KBLK 512          // k_minmax blocks

// ws layout (bytes):
//   ghist  at   256 : float[2][4096]   (zeroed by k_minmax; atomic-accumulated by k_gemm)
//   kblk   at 36864 : uint4[512]       (plain-stored by k_minmax)
#define OFF_GHIST 256
#define OFF_KBLK 36864

typedef int  v4i __attribute__((ext_vector_type(4)));

// monotone float->uint key: max over keys == max over floats
__device__ __forceinline__ unsigned fkey(float x){
    unsigned u = __float_as_uint(x);
    return (u & 0x80000000u) ? ~u : (u | 0x80000000u);
}
__device__ __forceinline__ float fdecode(unsigned k){
    return __uint_as_float((k & 0x80000000u) ? (k ^ 0x80000000u) : ~k);
}

// cubic B-spline weights for the 4 bins it0-1..it0+2, u = frac(vt) in [0,1)
__device__ __forceinline__ void bw4(float u, float w[4]){
    float um = 1.f - u;
    float u2 = u*u, um2 = um*um;
    w[0] = um2*um*(1.f/6.f);
    w[3] = u2*u*(1.f/6.f);
    w[1] = 0.6666666666666667f - u2 + 0.5f*u2*u;
    w[2] = 0.6666666666666667f - um2 + 0.5f*um2*um;
}

// per-block min/max -> plain store into kblk[block]; blocks 0..7 also zero ghist
__global__ void __launch_bounds__(256)
k_minmax(const float4* __restrict__ t4, const float4* __restrict__ s4,
         int n4, uint4* __restrict__ kblk, float* __restrict__ ghist){
    __shared__ unsigned red[4][4];   // [wave][key]

    if (blockIdx.x < 8)
        ghist[blockIdx.x*1024 + threadIdx.x] = 0.f,
        ghist[blockIdx.x*1024 + 256 + threadIdx.x] = 0.f,
        ghist[blockIdx.x*1024 + 512 + threadIdx.x] = 0.f,
        ghist[blockIdx.x*1024 + 768 + threadIdx.x] = 0.f;

    unsigned mt=0u, mnt=0u, ms=0u, mns=0u;
    int stride = gridDim.x * blockDim.x;
    for (int i = blockIdx.x*blockDim.x + threadIdx.x; i < n4; i += stride){
        float4 a = t4[i];
        float4 b = s4[i];
        mt  = max(mt,  max(max(fkey(a.x),  fkey(a.y)),  max(fkey(a.z),  fkey(a.w))));
        mnt = max(mnt, max(max(fkey(-a.x), fkey(-a.y)), max(fkey(-a.z), fkey(-a.w))));
        ms  = max(ms,  max(max(fkey(b.x),  fkey(b.y)),  max(fkey(b.z),  fkey(b.w))));
        mns = max(mns, max(max(fkey(-b.x), fkey(-b.y)), max(fkey(-b.z), fkey(-b.w))));
    }
    #pragma unroll
    for (int off = 32; off; off >>= 1){
        mt  = max(mt,  __shfl_down(mt,  off));
        mnt = max(mnt, __shfl_down(mnt, off));
        ms  = max(ms,  __shfl_down(ms,  off));
        mns = max(mns, __shfl_down(mns, off));
    }
    int wid = threadIdx.x >> 6;
    if ((threadIdx.x & 63) == 0){
        red[wid][0] = mt; red[wid][1] = mnt; red[wid][2] = ms; red[wid][3] = mns;
    }
    __syncthreads();
    if (threadIdx.x == 0){
        uint4 q;
        q.x = max(max(red[0][0], red[1][0]), max(red[2][0], red[3][0]));
        q.y = max(max(red[0][1], red[1][1]), max(red[2][1], red[3][1]));
        q.z = max(max(red[0][2], red[1][2]), max(red[2][2], red[3][2]));
        q.w = max(max(red[0][3], red[1][3]), max(red[2][3], red[3][3]));
        kblk[blockIdx.x] = q;
    }
}

// joint histogram as tall-skinny GEMM on int8 (wave-private LDS tiles, i8 MFMA).
// 4 waves/block, exactly 16 chunks/wave; depth-2 global prefetch; unroll-2 body.
// Epilogue: pairwise LDS merge (waves 0,1 -> fm0 ; waves 2,3 -> fm1) then
// global f32 atomic add into ghist (no partials, no reduce kernel).
__global__ void __launch_bounds__(256)
k_gemm(const float* __restrict__ t, const float* __restrict__ s,
       const uint4* __restrict__ kblk, float* __restrict__ ghist){
    __shared__ int4 smem4[2720];           // 43520 B = 4 waves * (A+B i8 tiles)
    __shared__ unsigned kred[4][4];

    int tid = threadIdx.x;
    int lane = tid & 63;
    int warp = tid >> 6;
    int rrow = lane & 15;                  // fragment row/col within 16-tile
    int kgrp = lane >> 4;                  // k-group (16 bytes each for K=64 i8)
    int b = blockIdx.y;

    char* As = (char*)smem4 + warp*WAVE_B; // this wave's tiles
    char* Bs = As + TILE_B;

    // initial clear of this wave's tiles (wave-private: no barrier needed)
    {
        int4* wz = (int4*)As;
        int4 z4 = {0,0,0,0};
        #pragma unroll
        for (int i = 0; i < 11; ++i){
            int idx = i*64 + lane;
            if (idx < WAVE_B/16) wz[idx] = z4;
        }
    }

    // reduce the 512 per-block key quads (redundant per block; ~L2-hit)
    {
        unsigned m0=0u, m1=0u, m2=0u, m3=0u;
        #pragma unroll
        for (int i = 0; i < 2; ++i){
            uint4 q = kblk[tid + i*256];
            m0 = max(m0, q.x); m1 = max(m1, q.y);
            m2 = max(m2, q.z); m3 = max(m3, q.w);
        }
        #pragma unroll
        for (int off = 32; off; off >>= 1){
            m0 = max(m0, __shfl_down(m0, off));
            m1 = max(m1, __shfl_down(m1, off));
            m2 = max(m2, __shfl_down(m2, off));
            m3 = max(m3, __shfl_down(m3, off));
        }
        if (lane == 0){
            kred[warp][0] = m0; kred[warp][1] = m1;
            kred[warp][2] = m2; kred[warp][3] = m3;
        }
        __syncthreads();
    }
    float tmax =  fdecode(max(max(kred[0][0], kred[1][0]), max(kred[2][0], kred[3][0])));
    float tmin = -fdecode(max(max(kred[0][1], kred[1][1]), max(kred[2][1], kred[3][1])));
    float smax =  fdecode(max(max(kred[0][2], kred[1][2]), max(kred[2][2], kred[3][2])));
    float smin = -fdecode(max(max(kred[0][3], kred[1][3]), max(kred[2][3], kred[3][3])));
    float tsc = 64.f / (tmax - tmin);
    float ssc = 64.f / (smax - smin);

    const float* tb = t + (size_t)b*BATCH_N;
    const float* sb = s + (size_t)b*BATCH_N;

    v4i acc[4][4];
    #pragma unroll
    for (int i = 0; i < 4; ++i)
        #pragma unroll
        for (int j = 0; j < 4; ++j)
            acc[i][j] = (v4i){0,0,0,0};

    int c0 = blockIdx.x*4 + warp;          // wave index within batch [0, 864)
    // depth-2 prefetch pipeline
    float tq0 = tb[(size_t)c0*64 + lane];
    float sq0 = sb[(size_t)c0*64 + lane];
    float tq1 = tb[(size_t)(c0 + GWAVES)*64 + lane];
    float sq1 = sb[(size_t)(c0 + GWAVES)*64 + lane];

    #pragma unroll 2
    for (int it = 0; it < 16; ++it){
        // issue prefetch for chunk it+2 (clamped to a safe in-range address)
        int cpre = c0 + (it < 14 ? (it + 2)*GWAVES : 0);
        float tnn = tb[(size_t)cpre*64 + lane];
        float snn = sb[(size_t)cpre*64 + lane];

        float vt = (tq0 - tmin) * tsc;     // in [0,64]
        float vs = (sq0 - smin) * ssc;
        int it0 = (int)floorf(vt);         // 0..64
        int is0 = (int)floorf(vs);
        float wt[4], wsv[4];
        bw4(vt - (float)it0, wt);
        bw4(vs - (float)is0, wsv);

        // quantized scatter: lane owns voxel column `lane`; padded rows it0..it0+3
        // (bin it0-1..it0+2 shifted +1), unconditional — pad rows are never read.
        char* pa = As + it0*ROWB + lane;
        char* pb = Bs + is0*ROWB + lane;
        #pragma unroll
        for (int k = 0; k < 4; ++k){
            pa[k*ROWB] = (char)__float2int_rn(wt[k]  * QS);
            pb[k*ROWB] = (char)__float2int_rn(wsv[k] * QS);
        }

        // fragments + MFMA (same-wave DS ops complete in order)
        v4i af[4], bf[4];
        #pragma unroll
        for (int m = 0; m < 4; ++m)
            af[m] = *(const v4i*)(As + (m*16 + rrow + 1)*ROWB + kgrp*16);
        #pragma unroll
        for (int n = 0; n < 4; ++n)
            bf[n] = *(const v4i*)(Bs + (n*16 + rrow + 1)*ROWB + kgrp*16);
        #pragma unroll
        for (int m = 0; m < 4; ++m)
            #pragma unroll
            for (int n = 0; n < 4; ++n)
                acc[m][n] = __builtin_amdgcn_mfma_i32_16x16x64_i8(af[m], bf[n], acc[m][n], 0, 0, 0);

        // zero-restore the scattered entries
        __asm__ volatile("" ::: "memory");
        #pragma unroll
        for (int k = 0; k < 4; ++k){
            pa[k*ROWB] = 0;
            pb[k*ROWB] = 0;
        }

        tq0 = tq1; sq0 = sq1;
        tq1 = tnn; sq1 = snn;
    }

    // merge: reuse tile LDS (dead now) as f32 staging.
    // pair p = warp>>1 uses region fm_p at smem + p*2*WAVE_B (16884 B <= 21760 B).
    // Even warp of the pair stores, odd warp adds; then cooperative global atomics.
    const float dq = 1.f / (QS*QS);
    float* fmw = (float*)((char*)smem4 + (warp >> 1)*(2*WAVE_B));
    __syncthreads();                       // all waves done reading their tiles
    if ((warp & 1) == 0){
        #pragma unroll
        for (int m = 0; m < 4; ++m)
            #pragma unroll
            for (int n = 0; n < 4; ++n)
                #pragma unroll
                for (int r = 0; r < 4; ++r)
                    fmw[(m*16 + kgrp*4 + r)*MROW + n*16 + rrow] = (float)acc[m][n][r] * dq;
    }
    __syncthreads();
    if ((warp & 1) == 1){
        #pragma unroll
        for (int m = 0; m < 4; ++m)
            #pragma unroll
            for (int n = 0; n < 4; ++n)
                #pragma unroll
                for (int r = 0; r < 4; ++r)
                    fmw[(m*16 + kgrp*4 + r)*MROW + n*16 + rrow] += (float)acc[m][n][r] * dq;
    }
    __syncthreads();
    // cooperative: sum the two pair-regions, atomic-add into ghist
    {
        const float* fm0 = (const float*)smem4;
        const float* fm1 = (const float*)((char*)smem4 + 2*WAVE_B);
        float* g = ghist + b*4096;
        #pragma unroll
        for (int i = 0; i < 16; ++i){
            int idx = i*256 + tid;
            int l = (idx >> 6)*MROW + (idx & 63);
            unsafeAtomicAdd(&g[idx], fm0[l] + fm1[l]);
        }
    }
}

__device__ __forceinline__ float blockReduceSum(float v, float* red){
    #pragma unroll
    for (int off = 32; off; off >>= 1) v += __shfl_down(v, off);
    int wid = threadIdx.x >> 6, lane = threadIdx.x & 63;
    __syncthreads();              // protect red[] from previous round
    if (lane == 0) red[wid] = v;
    __syncthreads();
    return red[0] + red[1] + red[2] + red[3];
}

__global__ void k_final(const float* __restrict__ hist, float* __restrict__ out){
    __shared__ float sh[2*4096];
    __shared__ float red[4];
    int tid = threadIdx.x;
    for (int i = tid; i < 8192; i += 256) sh[i] = hist[i];
    __syncthreads();

    float loc = 0.f;
    for (int i = tid; i < 8192; i += 256) loc += sh[i];
    float total = blockReduceSum(loc, red);
    float inv = 1.f / total;

    float nmi[2];
    for (int b = 0; b < 2; ++b){
        const float* h = sh + b*4096;
        float lj = 0.f;
        for (int i = tid; i < 4096; i += 256){
            float p = h[i]*inv;
            lj += p*logf(p + 1e-12f);
        }
        float Hj = -blockReduceSum(lj, red);
        float lt = 0.f;
        if (tid < 64){
            float r = 0.f;
            for (int j = 0; j < 64; ++j) r += h[tid*64 + j];
            float p = r*inv;
            lt = p*logf(p + 1e-12f);
        }
        float Ht = -blockReduceSum(lt, red);
        float ls = 0.f;
        if (tid < 64){
            float c = 0.f;
            for (int j = 0; j < 64; ++j) c += h[j*64 + tid];
            float p = c*inv;
            ls = p*logf(p + 1e-12f);
        }
        float Hs = -blockReduceSum(ls, red);
        nmi[b] = (Ht + Hs) / Hj;
    }
    if (tid == 0) out[0] = -0.5f*(nmi[0] + nmi[1]);
}

extern "C" void kernel_launch(void* const* d_in, const int* in_sizes, int n_in,
                              void* d_out, int out_size, void* d_ws, size_t ws_size,
                              hipStream_t stream) {
    const float* t = (const float*)d_in[0];
    const float* s = (const float*)d_in[1];
    float* out = (float*)d_out;
    float* ghist = (float*)((char*)d_ws + OFF_GHIST);
    uint4* kblk  = (uint4*)((char*)d_ws + OFF_KBLK);

    // no memset node: kblk plain-stored + ghist zeroed by k_minmax; k_gemm
    // atomically accumulates ghist. Kernel boundaries provide visibility.
    k_minmax<<<KBLK, 256, 0, stream>>>((const float4*)t, (const float4*)s, NTOT/4, kblk, ghist);
    k_gemm<<<dim3(GBLK, 2), 256, 0, stream>>>(t, s, kblk, ghist);
    k_final<<<1, 256, 0, stream>>>(ghist, out);
}